// Round 9
// baseline (158.107 us; speedup 1.0000x reference)
//
#include <hip/hip_runtime.h>

// WaveletFeatureAugmentation: passthrough + skinny MFMA GEMM, wave-autonomous.
//   aug[16384][14] = X[16384][4096] @ CM^T[4096][14] (bf16 MFMA 16x16x32).
// CM = W @ 9-level db4 cascade (adjoint builder verified rounds 3-8).
// Main kernel: 256 blocks x 256 thr; each WAVE owns 16 rows and ALL of k ->
// no cross-wave combine, ZERO barriers. Per 256-k tile: issue next tile's 16
// coalesced 1KB loads (stay in flight across the whole iteration), consume
// current tile from regs (passthrough stores + bf16 cvt + ds_write into the
// wave's private LDS tile), lgkmcnt fence, 8x(ds_read_b128 + MFMA).
// B-operand (CM) is pre-laid-out fragment-major: one contiguous 1KB load per
// MFMA step, L2-hot. Epilogue: wave writes its 16x14 aug directly.

#define ROWS 16384          // 32*512
#define N0   4096
#define OUTW 4110           // 4096 + 14
#define BK   256
#define ITERS (N0 / BK)     // 16
#define LROW 264            // LDS row stride in bf16 (528 B, 16B-aligned, padded)

typedef __attribute__((ext_vector_type(8))) short bf16x8;
typedef __attribute__((ext_vector_type(4))) float f32x4;

__device__ __constant__ float c_dlo[8] = {
    -0.010597401784997278f,  0.032883011666982945f,
     0.030841381835986965f, -0.18703481171888114f,
    -0.02798376941698385f,   0.6308807679295904f,
     0.7148465705525415f,    0.23037781330885523f};

__device__ __forceinline__ unsigned short f2bf(float f) {  // RNE float->bf16
    unsigned u = __float_as_uint(f);
    return (unsigned short)((u + 0x7FFFu + ((u >> 16) & 1u)) >> 16);
}

// ---- CM builder (adjoint cascade, verified rounds 3-8). Output layout is
// MFMA-fragment-major: for k-step S (K=32), lane l=(g<<4)|r reads bf16x8 at
// flat index (S*64 + l) -> element (row=r, k=32S+8g+j) at ((S<<6)+(g<<4)+r)*8+j.
__device__ __forceinline__ float adj_contrib(const float* __restrict__ g,
                                             int t, int nout) {
    int i0 = t >> 1;        if (i0 < 0) i0 = 0;
    int i1 = (t + 6) >> 1;  if (i1 > nout - 1) i1 = nout - 1;
    float acc = 0.f;
    for (int i = i0; i <= i1; ++i)
        acc = fmaf(g[i], c_dlo[2 * i + 1 - t], acc);
    return acc;
}

__global__ __launch_bounds__(256) void build_cm_kernel(
    const float* __restrict__ W, unsigned short* __restrict__ cmB)
{
    __shared__ float A[4096];
    __shared__ float B[2051];
    const int o = blockIdx.x, tid = threadIdx.x;   // o in [0,16)
    if (tid < 14) B[tid] = (o < 14) ? W[o * 14 + tid] : 0.f;
    __syncthreads();
    const int ns[10] = {14, 22, 38, 70, 134, 262, 518, 1029, 2051, 4096};
    float* g = B;
    float* h = A;
    for (int lev = 1; lev <= 9; ++lev) {
        const int n = ns[lev], nout = ns[lev - 1];
        const int s2 = 2 * (n - nout);
        for (int s = tid; s < n; s += 256) {
            float v = adj_contrib(g, s, nout);
            if (s <= 5)  v += adj_contrib(g, -1 - s, nout);
            if (s >= s2) v += adj_contrib(g, 2 * n - 1 - s, nout);
            h[s] = v;
        }
        __syncthreads();
        float* t2 = g; g = h; h = t2;
    }
    for (int c = tid; c < 4096; c += 256) {
        const int S = c >> 5, gg = (c >> 3) & 3, j = c & 7;
        cmB[(((S << 6) + (gg << 4) + o) << 3) + j] = f2bf(g[c]);
    }
}

// ---- main fused kernel: zero barriers ----
__global__ __launch_bounds__(256) void wavelet_aug_mfma(
    const float* __restrict__ x, const unsigned short* __restrict__ cmB,
    const float* __restrict__ b, float* __restrict__ out)
{
    __shared__ __align__(16) unsigned short xt[4][16][LROW];  // per-wave tile

    const int tid  = threadIdx.x;
    const int wave = tid >> 6;
    const int lane = tid & 63;
    const int r    = lane & 15;            // A row / B col within fragment
    const int g    = lane >> 4;            // k-subgroup
    const int wr0  = (blockIdx.x << 6) + (wave << 4);   // wave's first row

    const float* xw  = x   + (size_t)wr0 * N0 + (lane << 2);
    float*       ow  = out + (size_t)wr0 * OUTW + (lane << 2);
    const bf16x8* cb = reinterpret_cast<const bf16x8*>(cmB);
    unsigned short* lds = &xt[wave][0][0];

    f32x4 acc = {0.f, 0.f, 0.f, 0.f};

    float4 tile[16];
    #pragma unroll
    for (int i = 0; i < 16; ++i)
        tile[i] = *reinterpret_cast<const float4*>(xw + (size_t)i * N0);

    #pragma unroll 1
    for (int it = 0; it < ITERS; ++it) {
        const int kb = it << 8;

        // issue next tile's loads (stay in flight across this iteration)
        float4 nxt[16];
        if (it < ITERS - 1) {
            #pragma unroll
            for (int i = 0; i < 16; ++i)
                nxt[i] = *reinterpret_cast<const float4*>(
                    xw + (size_t)i * N0 + kb + BK);
        }
        // B fragments for this iteration (contiguous 1KB/instr, L2-hot)
        bf16x8 bv[8];
        #pragma unroll
        for (int s = 0; s < 8; ++s)
            bv[s] = cb[(((it << 3) + s) << 6) + lane];

        // consume current tile: passthrough stores + cvt + ds_write
        #pragma unroll
        for (int i = 0; i < 16; ++i) {
            const float4 a = tile[i];
            float* orow = ow + (size_t)i * OUTW + kb;
            if (i & 1) {   // row base 8B-aligned
                reinterpret_cast<float2*>(orow)[0] = make_float2(a.x, a.y);
                reinterpret_cast<float2*>(orow)[1] = make_float2(a.z, a.w);
            } else {       // row base 16B-aligned
                *reinterpret_cast<float4*>(orow) = a;
            }
            ushort4 u;
            u.x = f2bf(a.x); u.y = f2bf(a.y); u.z = f2bf(a.z); u.w = f2bf(a.w);
            *reinterpret_cast<ushort4*>(lds + i * LROW + (lane << 2)) = u;
        }

        // wave-local LDS ordering: writes done before fragment reads
        asm volatile("s_waitcnt lgkmcnt(0)" ::: "memory");
        __builtin_amdgcn_sched_barrier(0);

        #pragma unroll
        for (int s = 0; s < 8; ++s) {
            const bf16x8 av = *reinterpret_cast<const bf16x8*>(
                lds + r * LROW + (s << 5) + (g << 3));
            acc = __builtin_amdgcn_mfma_f32_16x16x32_bf16(av, bv[s], acc, 0, 0, 0);
        }

        #pragma unroll
        for (int i = 0; i < 16; ++i) tile[i] = nxt[i];
    }

    // epilogue: C/D map col=lane&15, row=4*(lane>>4)+j (verified rounds 7-8)
    const int col = lane & 15;
    if (col < 14) {
        const float bb = b[col];
        #pragma unroll
        for (int j = 0; j < 4; ++j) {
            const int row = wr0 + ((lane >> 4) << 2) + j;
            out[(size_t)row * OUTW + N0 + col] = acc[j] + bb;
        }
    }
}

extern "C" void kernel_launch(void* const* d_in, const int* in_sizes, int n_in,
                              void* d_out, int out_size, void* d_ws, size_t ws_size,
                              hipStream_t stream) {
    const float* x = (const float*)d_in[0];   // [32,512,4096]
    const float* W = (const float*)d_in[1];   // [14,14]
    const float* b = (const float*)d_in[2];   // [14]
    float* out = (float*)d_out;               // [32,512,4110]
    unsigned short* cmB = (unsigned short*)d_ws;  // [128K] bf16, fragment-major

    build_cm_kernel<<<16, 256, 0, stream>>>(W, cmB);
    wavelet_aug_mfma<<<ROWS / 64, 256, 0, stream>>>(x, cmB, b, out);
}